// Round 16
// baseline (336.628 us; speedup 1.0000x reference)
//
#include <hip/hip_runtime.h>
#include <hip/hip_bf16.h>

#define DI __device__ __forceinline__

typedef __attribute__((ext_vector_type(8))) __bf16 bf16x8;
typedef __attribute__((ext_vector_type(4))) float f32x4;
typedef __attribute__((ext_vector_type(4))) unsigned short u16x4;
typedef __attribute__((ext_vector_type(8))) unsigned short u16x8;

DI unsigned short f2bs(float f) {
  __hip_bfloat16 h = __float2bfloat16(f);
  return __builtin_bit_cast(unsigned short, h);
}
DI float bs2f(unsigned short s) {
  return __bfloat162float(__builtin_bit_cast(__hip_bfloat16, s));
}
DI f32x4 mfma16(bf16x8 a, bf16x8 b, f32x4 c) {
  return __builtin_amdgcn_mfma_f32_16x16x32_bf16(a, b, c, 0, 0, 0);
}
DI void g2lds16(const void* g, void* l) {
  __builtin_amdgcn_global_load_lds(
      (__attribute__((address_space(1))) void*)(unsigned long long)g,
      (__attribute__((address_space(3))) void*)l, 16, 0, 0);
}
#define SB __builtin_amdgcn_sched_barrier(0)
DI void barrier_lgkm() {
  asm volatile("s_waitcnt lgkmcnt(0)" ::: "memory");
  SB;
  __builtin_amdgcn_s_barrier();
  SB;
}
DI void vm_guard3() {
  SB;
  asm volatile("s_waitcnt vmcnt(3)" ::: "memory");
  SB;
}

// ---------------- weight transpose f32[K,N] -> bf16[N,K] ----------------
__global__ __launch_bounds__(256) void k_transw(const float* __restrict__ W,
                                                unsigned short* __restrict__ Wt,
                                                int K, int N) {
  __shared__ float tile[64][65];
  int tk = blockIdx.x * 64, tn = blockIdx.y * 64;
  int t = threadIdx.x;
#pragma unroll
  for (int i = 0; i < 16; ++i) {
    int idx = t + i * 256;
    int r = idx >> 6, c = idx & 63;
    tile[r][c] = W[(size_t)(tk + r) * N + tn + c];
  }
  __syncthreads();
#pragma unroll
  for (int i = 0; i < 16; ++i) {
    int idx = t + i * 256;
    int n = idx >> 6, kk = idx & 63;
    Wt[(size_t)(tn + n) * K + tk + kk] = f2bs(tile[kk][n]);
  }
}

// ---------------- bias concat [bq|bk|bv|bg] -> bcat[2048] ----------------
__global__ __launch_bounds__(256) void k_bcat(const float* __restrict__ bq,
                                              const float* __restrict__ bk,
                                              const float* __restrict__ bv,
                                              const float* __restrict__ bg,
                                              float* __restrict__ bcat) {
  int t = blockIdx.x * 256 + threadIdx.x;
  const float* src = t < 512 ? bq : t < 1024 ? bk : t < 1536 ? bv : bg;
  bcat[t] = src[t & 511];
}

// ---------------- LayerNorm f32[rows,512] -> bf16 ----------------
__global__ __launch_bounds__(256) void k_ln(const float* __restrict__ x,
                                            const float* __restrict__ g,
                                            const float* __restrict__ b,
                                            unsigned short* __restrict__ y) {
  int row = blockIdx.x, t = threadIdx.x;
  const float* xr = x + (size_t)row * 512;
  float a0 = xr[t], a1 = xr[t + 256];
  float s1 = a0 + a1, s2 = a0 * a0 + a1 * a1;
#pragma unroll
  for (int o = 32; o > 0; o >>= 1) {
    s1 += __shfl_down(s1, o);
    s2 += __shfl_down(s2, o);
  }
  __shared__ float r1[4], r2[4], bc[2];
  int w = t >> 6, l = t & 63;
  if (l == 0) { r1[w] = s1; r2[w] = s2; }
  __syncthreads();
  if (t == 0) {
    float t1 = r1[0] + r1[1] + r1[2] + r1[3];
    float t2 = r2[0] + r2[1] + r2[2] + r2[3];
    float m = t1 / 512.f;
    float v = t2 / 512.f - m * m;
    bc[0] = m;
    bc[1] = rsqrtf(v + 1e-5f);
  }
  __syncthreads();
  float m = bc[0], inv = bc[1];
  y[(size_t)row * 512 + t] = f2bs((a0 - m) * inv * g[t] + b[t]);
  y[(size_t)row * 512 + t + 256] = f2bs((a1 - m) * inv * g[t + 256] + b[t + 256]);
}

// ---------------- GEMM 128x128 (m97 structure): C = A[M,K]*Bt[N,K]^T + bias ----------------
__global__ __launch_bounds__(256) void k_gemm2(
    const unsigned short* __restrict__ A, const unsigned short* __restrict__ Bt,
    const float* __restrict__ bias, int M, int N, int K, int mode,
    float* __restrict__ outf, unsigned short* __restrict__ outh,
    const float* __restrict__ add1, const float* __restrict__ add2,
    unsigned short* __restrict__ vtout) {
  __shared__ __align__(16) unsigned short lA[128 * 64];
  __shared__ __align__(16) unsigned short lB[128 * 64];
  int t = threadIdx.x, w = t >> 6, l = t & 63;
  int l15 = l & 15, lg = l >> 4;
  int m0 = blockIdx.x * 128, n0 = blockIdx.y * 128;
  int wm = (w >> 1) * 64, wn = (w & 1) * 64;
  f32x4 acc[4][4] = {};
  int srow = w * 32 + (l >> 3);
  int scolb = (l & 7) * 16;
  for (int k0 = 0; k0 < K; k0 += 64) {
#pragma unroll
    for (int c = 0; c < 4; ++c) {
      int row = srow + c * 8;
      g2lds16((const char*)A + ((size_t)(m0 + row) * K + k0) * 2 + scolb,
              (char*)lA + w * 4096 + c * 1024);
      g2lds16((const char*)Bt + ((size_t)(n0 + row) * K + k0) * 2 + scolb,
              (char*)lB + w * 4096 + c * 1024);
    }
    __syncthreads();
#pragma unroll
    for (int kc = 0; kc < 2; ++kc) {
      bf16x8 af[4], bfr[4];
#pragma unroll
      for (int i = 0; i < 4; ++i) {
        af[i] = *(const bf16x8*)((const char*)lA + (wm + i * 16 + l15) * 128 + kc * 64 + lg * 16);
        bfr[i] = *(const bf16x8*)((const char*)lB + (wn + i * 16 + l15) * 128 + kc * 64 + lg * 16);
      }
#pragma unroll
      for (int i = 0; i < 4; ++i)
#pragma unroll
        for (int j = 0; j < 4; ++j)
          acc[i][j] = mfma16(af[i], bfr[j], acc[i][j]);
    }
    __syncthreads();
  }
#pragma unroll
  for (int i = 0; i < 4; ++i) {
#pragma unroll
    for (int j = 0; j < 4; ++j) {
      int col = n0 + wn + j * 16 + l15;
      int row0 = m0 + wm + i * 16 + lg * 4;
      float vals[4];
#pragma unroll
      for (int r = 0; r < 4; ++r) vals[r] = acc[i][j][r] + bias[col];
      if (mode == 6) {
        int sel = col >> 9, c5 = col & 511;
        if (sel == 2) {
          int hh = c5 >> 6, dd = c5 & 63, bb = row0 >> 11, nn = row0 & 2047;
          u16x4 pk;
#pragma unroll
          for (int r = 0; r < 4; ++r) pk[r] = f2bs(vals[r]);
          *(u16x4*)(vtout + (((size_t)(bb * 8 + hh) * 64 + dd) * 2048 + nn)) = pk;
        } else {
#pragma unroll
          for (int r = 0; r < 4; ++r) {
            size_t idx = (size_t)(row0 + r) * 512 + c5;
            if (sel == 0) outh[idx] = f2bs(vals[r] * 0.125f);
            else if (sel == 1) outh[2097152 + idx] = f2bs(vals[r]);
            else outf[idx] = bs2f(A[idx]) * (1.f / (1.f + __expf(-vals[r])));
          }
        }
      } else {
#pragma unroll
        for (int r = 0; r < 4; ++r) {
          size_t idx = (size_t)(row0 + r) * N + col;
          if (mode == 3) outf[idx] = vals[r] + add1[idx] + add2[idx];
          else if (mode == 4) outh[idx] = f2bs(0.5f * vals[r] * (1.f + erff(vals[r] * 0.70710678f)));
          else outf[idx] = vals[r] + add1[idx];
        }
      }
    }
  }
}

// ---------------- flash attention v15: attn14 + conflict-free lsB pitch ----------------
// lsB layout: [q][k][h] with k-stride 20B (8h x 2B + 4B pad) and row pitch 648B.
// Bank: lane l15 -> 5*l15 mod 32 (16 distinct), lg -> +2*qr => worst-case 2-way (free).
// Everything else identical to R15's k_attn14 (full-iter bias prefetch, counted vmcnt,
// lgkm-only barriers, LDS-staged K/V with XOR swizzle).
#define BPITCH 648
#define KSTR 20
__global__ __launch_bounds__(512, 1) void k_attn15(
    const unsigned short* __restrict__ q, const unsigned short* __restrict__ kk,
    const unsigned short* __restrict__ vt, const float* __restrict__ bias,
    const unsigned char* __restrict__ mask, unsigned short* __restrict__ ao) {
  __shared__ __align__(16) char lsK[2][32768];
  __shared__ __align__(16) char lsV[2][32768];
  __shared__ __align__(16) char lsB[2][16 * BPITCH];
  __shared__ __align__(16) unsigned short ls_p[8][16][36];

  int bid = blockIdx.x;
  int b = bid >> 7, qt = bid & 127;
  int q0 = qt * 16;
  int t = threadIdx.x, w = t >> 6, l = t & 63;
  int l15 = l & 15, lg = l >> 4;
  int h = w;

  bf16x8 qa0 = *(const bf16x8*)(q + ((size_t)(b * 2048 + q0 + l15) * 512 + h * 64 + lg * 8));
  bf16x8 qa1 = *(const bf16x8*)(q + ((size_t)(b * 2048 + q0 + l15) * 512 + h * 64 + 32 + lg * 8));

  union { bf16x8 v; unsigned short s[8]; } uo;
#pragma unroll
  for (int j = 0; j < 8; ++j) uo.s[j] = 0x3F80;  // bf16 1.0
  const bf16x8 vones = uo.v;

  f32x4 oacc[4] = {};
  f32x4 lacc = {};

  const char* kptr[4];
  char* kdst[4];
#pragma unroll
  for (int i = 0; i < 4; ++i) {
    int fi = t + i * 512;
    int row = fi >> 6;
    int colb = ((fi & 63) * 16) ^ ((row & 7) << 4);
    kptr[i] = (const char*)kk + ((size_t)(b * 2048 + row) * 512) * 2 + colb;
    kdst[i] = (char*)0 + (i * 512 + w * 64) * 16;
  }
  const char* vptr[4];
#pragma unroll
  for (int i = 0; i < 4; ++i) {
    int fi = t + i * 512;
    int rv = fi >> 2;
    int dv = rv & 63, hv = rv >> 6;
    int slot = (fi & 3) ^ (dv & 3);
    vptr[i] = (const char*)vt + (((size_t)(b * 8 + hv) * 64 + dv) * 2048 + slot * 8) * 2;
  }
  int qq = t >> 5, kc = t & 31;
  const float* bptr = bias + ((size_t)(b * 2048 + q0 + qq) * 2048 + kc) * 8;
  const unsigned char* mptr = mask + (size_t)(b * 2048 + q0 + qq) * 2048 + kc;
  char* bdst = (char*)0 + qq * BPITCH + kc * KSTR;
  const unsigned short BN = f2bs(-1e30f);

#define STAGEKV(buf, kb)                                                     \
  do {                                                                       \
    _Pragma("unroll") for (int i = 0; i < 4; ++i)                            \
        g2lds16(kptr[i] + (size_t)(kb) * 1024, lsK[buf] + (size_t)kdst[i]);  \
    _Pragma("unroll") for (int i = 0; i < 4; ++i)                            \
        g2lds16(vptr[i] + (size_t)(kb) * 2, lsV[buf] + (size_t)kdst[i]);     \
  } while (0)
#define LOADB(BA, BB, MB, kb)                                                \
  do {                                                                       \
    BA = *(const float4*)(bptr + (size_t)(kb) * 8);                          \
    BB = *(const float4*)(bptr + (size_t)(kb) * 8 + 4);                      \
    MB = mptr[kb];                                                           \
  } while (0)
#define WRITEB(buf, BA, BB, MB)                                              \
  do {                                                                       \
    unsigned d0, d1, d2, d3;                                                 \
    if (MB) {                                                                \
      d0 = d1 = d2 = d3 = ((unsigned)BN << 16) | BN;                         \
    } else {                                                                 \
      d0 = f2bs(BA.x) | ((unsigned)f2bs(BA.y) << 16);                        \
      d1 = f2bs(BA.z) | ((unsigned)f2bs(BA.w) << 16);                        \
      d2 = f2bs(BB.x) | ((unsigned)f2bs(BB.y) << 16);                        \
      d3 = f2bs(BB.z) | ((unsigned)f2bs(BB.w) << 16);                        \
    }                                                                        \
    unsigned* bp_ = (unsigned*)(lsB[buf] + (size_t)bdst);                    \
    bp_[0] = d0; bp_[1] = d1; bp_[2] = d2; bp_[3] = d3;                      \
  } while (0)
#define LDSK(buf, tt, kcc)                                                   \
  (*(const bf16x8*)(lsK[buf] + ((tt)*16 + l15) * 1024 +                      \
                    ((h * 128 + (kcc)*64 + lg * 16) ^ ((((tt)*16 + l15) & 7) << 4))))
#define LDSV(buf, dt)                                                        \
  (*(const bf16x8*)(lsV[buf] +                                               \
                    (((h * 64 + (dt)*16 + l15) * 4 +                         \
                      (lg ^ (((dt)*16 + l15) & 3))) * 16)))
#define COMPUTE(buf)                                                         \
  do {                                                                       \
    f32x4 sc0 = {}, sc1 = {};                                                \
    sc0 = mfma16(qa0, LDSK(buf, 0, 0), sc0);                                 \
    sc0 = mfma16(qa1, LDSK(buf, 0, 1), sc0);                                 \
    sc1 = mfma16(qa0, LDSK(buf, 1, 0), sc1);                                 \
    sc1 = mfma16(qa1, LDSK(buf, 1, 1), sc1);                                 \
    _Pragma("unroll") for (int r = 0; r < 4; ++r) {                          \
      int qr = lg * 4 + r;                                                   \
      float b0 = bs2f(*(const unsigned short*)(lsB[buf] + qr * BPITCH + l15 * KSTR + h * 2));        \
      float b1 = bs2f(*(const unsigned short*)(lsB[buf] + qr * BPITCH + (l15 + 16) * KSTR + h * 2)); \
      float p0 = __expf(sc0[r] + b0 - 8.0f);                                 \
      float p1 = __expf(sc1[r] + b1 - 8.0f);                                 \
      ls_p[w][qr][l15] = f2bs(p0);                                           \
      ls_p[w][qr][16 + l15] = f2bs(p1);                                      \
    }                                                                        \
    bf16x8 pa = *(const bf16x8*)&ls_p[w][l15][lg * 8];                       \
    oacc[0] = mfma16(pa, LDSV(buf, 0), oacc[0]);                             \
    oacc[1] = mfma16(pa, LDSV(buf, 1), oacc[1]);                             \
    oacc[2] = mfma16(pa, LDSV(buf, 2), oacc[2]);                             \
    oacc[3] = mfma16(pa, LDSV(buf, 3), oacc[3]);                             \
    lacc = mfma16(pa, vones, lacc);                                          \
  } while (0)

  float4 rA0, rA1, rB0, rB1;
  unsigned char mA, mB;
  LOADB(rA0, rA1, mA, 0);
  WRITEB(0, rA0, rA1, mA);
  LOADB(rB0, rB1, mB, 32);
  SB;
  STAGEKV(0, 0);
  SB;
  vm_guard3();
  barrier_lgkm();
  for (int it = 0; it < 64; it += 2) {
    int kb1 = (it + 1) * 32;
    int kb2 = (it + 2 < 64) ? (it + 2) * 32 : 0;
    int kb3 = (it + 3 < 64) ? (it + 3) * 32 : 0;
    SB;
    STAGEKV(1, kb1);
    SB;
    LOADB(rA0, rA1, mA, kb2);
    SB;
    COMPUTE(0);
    WRITEB(1, rB0, rB1, mB);
    vm_guard3();
    barrier_lgkm();
    SB;
    STAGEKV(0, kb2);
    SB;
    LOADB(rB0, rB1, mB, kb3);
    SB;
    COMPUTE(1);
    WRITEB(0, rA0, rA1, mA);
    vm_guard3();
    barrier_lgkm();
  }
#undef STAGEKV
#undef LOADB
#undef WRITEB
#undef LDSK
#undef LDSV
#undef COMPUTE

#pragma unroll
  for (int d = 0; d < 4; ++d)
#pragma unroll
    for (int r = 0; r < 4; ++r) {
      size_t row = (size_t)(b * 2048 + q0 + lg * 4 + r);
      ao[row * 512 + h * 64 + d * 16 + l15] = f2bs(oacc[d][r] / lacc[r]);
    }
}

extern "C" void kernel_launch(void* const* d_in, const int* in_sizes, int n_in,
                              void* d_out, int out_size, void* d_ws, size_t ws_size,
                              hipStream_t stream) {
  (void)in_sizes; (void)n_in; (void)out_size; (void)ws_size;
  const float* x = (const float*)d_in[0];
  const float* abias = (const float*)d_in[1];
  const unsigned char* amask = (const unsigned char*)d_in[2];
  const float* Wq = (const float*)d_in[3];
  const float* bq = (const float*)d_in[4];
  const float* Wk = (const float*)d_in[5];
  const float* bk = (const float*)d_in[6];
  const float* Wv = (const float*)d_in[7];
  const float* bv = (const float*)d_in[8];
  const float* Wg = (const float*)d_in[9];
  const float* bg = (const float*)d_in[10];
  const float* Wo = (const float*)d_in[11];
  const float* bo = (const float*)d_in[12];
  const float* ln1g = (const float*)d_in[13];
  const float* ln1b = (const float*)d_in[14];
  const float* ln2g = (const float*)d_in[15];
  const float* ln2b = (const float*)d_in[16];
  const float* W1 = (const float*)d_in[17];
  const float* b1 = (const float*)d_in[18];
  const float* W2 = (const float*)d_in[19];
  const float* b2 = (const float*)d_in[20];
  float* outp = (float*)d_out;

  char* ws = (char*)d_ws;
  const size_t MB = 1024 * 1024;

  unsigned short* qb = (unsigned short*)(ws + 0);          // 4MB [4096][512]
  unsigned short* kb = (unsigned short*)(ws + 4 * MB);     // 4MB
  unsigned short* ao = (unsigned short*)(ws + 8 * MB);     // 4MB
  unsigned short* y1 = (unsigned short*)(ws + 28 * MB);    // 4MB
  unsigned short* h1 = (unsigned short*)(ws + 0);          // 16MB FFN phase
  float* u = (float*)(ws + 32 * MB);                       // 8MB
  unsigned short* wcat = (unsigned short*)(ws + 40 * MB);  // 2MB
  unsigned short* wot = (unsigned short*)(ws + 42 * MB);   // 0.5MB
  unsigned short* w1t = (unsigned short*)(ws + 42 * MB + 512 * 1024);
  unsigned short* w2t = (unsigned short*)(ws + 44 * MB + 512 * 1024);
  float* bcat = (float*)(ws + 46 * MB + 512 * 1024);
  unsigned short* vtb = (unsigned short*)(ws + 48 * MB);   // 4MB [2][8][64][2048]
  float* x2 = (float*)d_out;

  k_transw<<<dim3(8, 8), 256, 0, stream>>>(Wq, wcat + 0 * 512 * 512, 512, 512);
  k_transw<<<dim3(8, 8), 256, 0, stream>>>(Wk, wcat + 1 * 512 * 512, 512, 512);
  k_transw<<<dim3(8, 8), 256, 0, stream>>>(Wv, wcat + 2 * 512 * 512, 512, 512);
  k_transw<<<dim3(8, 8), 256, 0, stream>>>(Wg, wcat + 3 * 512 * 512, 512, 512);
  k_transw<<<dim3(8, 8), 256, 0, stream>>>(Wo, wot, 512, 512);
  k_transw<<<dim3(8, 32), 256, 0, stream>>>(W1, w1t, 512, 2048);
  k_transw<<<dim3(32, 8), 256, 0, stream>>>(W2, w2t, 2048, 512);
  k_bcat<<<8, 256, 0, stream>>>(bq, bk, bv, bg, bcat);

  k_ln<<<4096, 256, 0, stream>>>(x, ln1g, ln1b, y1);
  k_gemm2<<<dim3(32, 16), 256, 0, stream>>>(y1, wcat, bcat, 4096, 2048, 512, 6,
                                            u, qb, nullptr, nullptr, vtb);
  k_attn15<<<256, 512, 0, stream>>>(qb, kb, vtb, abias, amask, ao);
  k_gemm2<<<dim3(32, 4), 256, 0, stream>>>(ao, wot, bo, 4096, 512, 512, 3,
                                           x2, nullptr, u, x, nullptr);
  k_ln<<<4096, 256, 0, stream>>>(x2, ln2g, ln2b, y1);
  k_gemm2<<<dim3(32, 16), 256, 0, stream>>>(y1, w1t, b1, 4096, 2048, 512, 4,
                                            nullptr, h1, nullptr, nullptr, nullptr);
  k_gemm2<<<dim3(32, 4), 256, 0, stream>>>(h1, w2t, b2, 4096, 512, 2048, 5,
                                           outp, nullptr, x2, nullptr, nullptr);
}

// Round 19
// 257.905 us; speedup vs baseline: 1.3052x; 1.3052x over previous
//
#include <hip/hip_runtime.h>
#include <hip/hip_bf16.h>

#define DI __device__ __forceinline__

typedef __attribute__((ext_vector_type(8))) __bf16 bf16x8;
typedef __attribute__((ext_vector_type(4))) float f32x4;
typedef __attribute__((ext_vector_type(4))) unsigned short u16x4;
typedef __attribute__((ext_vector_type(8))) unsigned short u16x8;

DI unsigned short f2bs(float f) {
  __hip_bfloat16 h = __float2bfloat16(f);
  return __builtin_bit_cast(unsigned short, h);
}
DI float bs2f(unsigned short s) {
  return __bfloat162float(__builtin_bit_cast(__hip_bfloat16, s));
}
DI f32x4 mfma16(bf16x8 a, bf16x8 b, f32x4 c) {
  return __builtin_amdgcn_mfma_f32_16x16x32_bf16(a, b, c, 0, 0, 0);
}
DI void g2lds16(const void* g, void* l) {
  __builtin_amdgcn_global_load_lds(
      (__attribute__((address_space(1))) void*)(unsigned long long)g,
      (__attribute__((address_space(3))) void*)l, 16, 0, 0);
}
#define SB __builtin_amdgcn_sched_barrier(0)
DI void barrier_lgkm() {
  asm volatile("s_waitcnt lgkmcnt(0)" ::: "memory");
  SB;
  __builtin_amdgcn_s_barrier();
  SB;
}
DI void vm_guard3() {
  SB;
  asm volatile("s_waitcnt vmcnt(3)" ::: "memory");
  SB;
}

// ---------------- batched weight transpose (5x 512x512) f32[K,N] -> bf16[N,K] ----------------
__global__ __launch_bounds__(256) void k_transw5(
    const float* __restrict__ W0, const float* __restrict__ W1,
    const float* __restrict__ W2, const float* __restrict__ W3,
    const float* __restrict__ W4, unsigned short* __restrict__ wcat,
    unsigned short* __restrict__ wot) {
  __shared__ float tile[64][65];
  int z = blockIdx.z;
  const float* W = z == 0 ? W0 : z == 1 ? W1 : z == 2 ? W2 : z == 3 ? W3 : W4;
  unsigned short* Wt = z < 4 ? wcat + (size_t)z * 512 * 512 : wot;
  int tk = blockIdx.x * 64, tn = blockIdx.y * 64;
  int t = threadIdx.x;
#pragma unroll
  for (int i = 0; i < 16; ++i) {
    int idx = t + i * 256;
    int r = idx >> 6, c = idx & 63;
    tile[r][c] = W[(size_t)(tk + r) * 512 + tn + c];
  }
  __syncthreads();
#pragma unroll
  for (int i = 0; i < 16; ++i) {
    int idx = t + i * 256;
    int n = idx >> 6, kk = idx & 63;
    Wt[(size_t)(tn + n) * 512 + tk + kk] = f2bs(tile[kk][n]);
  }
}

// ---------------- weight transpose f32[K,N] -> bf16[N,K] (generic) ----------------
__global__ __launch_bounds__(256) void k_transw(const float* __restrict__ W,
                                                unsigned short* __restrict__ Wt,
                                                int K, int N) {
  __shared__ float tile[64][65];
  int tk = blockIdx.x * 64, tn = blockIdx.y * 64;
  int t = threadIdx.x;
#pragma unroll
  for (int i = 0; i < 16; ++i) {
    int idx = t + i * 256;
    int r = idx >> 6, c = idx & 63;
    tile[r][c] = W[(size_t)(tk + r) * N + tn + c];
  }
  __syncthreads();
#pragma unroll
  for (int i = 0; i < 16; ++i) {
    int idx = t + i * 256;
    int n = idx >> 6, kk = idx & 63;
    Wt[(size_t)(tn + n) * K + tk + kk] = f2bs(tile[kk][n]);
  }
}

// ---------------- bias concat [bq|bk|bv|bg] -> bcat[2048] ----------------
__global__ __launch_bounds__(256) void k_bcat(const float* __restrict__ bq,
                                              const float* __restrict__ bk,
                                              const float* __restrict__ bv,
                                              const float* __restrict__ bg,
                                              float* __restrict__ bcat) {
  int t = blockIdx.x * 256 + threadIdx.x;
  const float* src = t < 512 ? bq : t < 1024 ? bk : t < 1536 ? bv : bg;
  bcat[t] = src[t & 511];
}

// ---------------- LayerNorm f32[rows,512] -> bf16 ----------------
__global__ __launch_bounds__(256) void k_ln(const float* __restrict__ x,
                                            const float* __restrict__ g,
                                            const float* __restrict__ b,
                                            unsigned short* __restrict__ y) {
  int row = blockIdx.x, t = threadIdx.x;
  const float* xr = x + (size_t)row * 512;
  float a0 = xr[t], a1 = xr[t + 256];
  float s1 = a0 + a1, s2 = a0 * a0 + a1 * a1;
#pragma unroll
  for (int o = 32; o > 0; o >>= 1) {
    s1 += __shfl_down(s1, o);
    s2 += __shfl_down(s2, o);
  }
  __shared__ float r1[4], r2[4], bc[2];
  int w = t >> 6, l = t & 63;
  if (l == 0) { r1[w] = s1; r2[w] = s2; }
  __syncthreads();
  if (t == 0) {
    float t1 = r1[0] + r1[1] + r1[2] + r1[3];
    float t2 = r2[0] + r2[1] + r2[2] + r2[3];
    float m = t1 / 512.f;
    float v = t2 / 512.f - m * m;
    bc[0] = m;
    bc[1] = rsqrtf(v + 1e-5f);
  }
  __syncthreads();
  float m = bc[0], inv = bc[1];
  y[(size_t)row * 512 + t] = f2bs((a0 - m) * inv * g[t] + b[t]);
  y[(size_t)row * 512 + t + 256] = f2bs((a1 - m) * inv * g[t + 256] + b[t + 256]);
}

// ---------------- GEMM: C[M,N] = A[M,K](bf16) * Bt[N,K]^T + bias (R15 config) ----------------
template <int BM>
__global__ __launch_bounds__(256) void k_gemm(
    const unsigned short* __restrict__ A, const unsigned short* __restrict__ Bt,
    const float* __restrict__ bias, int M, int N, int K, int mode,
    float* __restrict__ outf, unsigned short* __restrict__ outh,
    const float* __restrict__ add1, const float* __restrict__ add2,
    unsigned short* __restrict__ vtout) {
  constexpr int MI = BM / 32;
  __shared__ __align__(16) unsigned short lA[BM * 64];
  __shared__ __align__(16) unsigned short lB[64 * 64];
  int t = threadIdx.x, w = t >> 6, l = t & 63;
  int l15 = l & 15, lg = l >> 4;
  int m0 = blockIdx.x * BM, n0 = blockIdx.y * 64;
  int wm = (w >> 1) * (BM / 2), wn = (w & 1) * 32;
  f32x4 acc[MI][2] = {};
  int sr = l >> 3, scb = (l & 7) * 16;
  for (int k0 = 0; k0 < K; k0 += 64) {
#pragma unroll
    for (int c = 0; c < MI; ++c) {
      int row = w * (BM / 4) + sr + c * 8;
      g2lds16((const char*)A + ((size_t)(m0 + row) * K + k0) * 2 + scb,
              (char*)lA + w * (BM / 4) * 128 + c * 1024);
    }
#pragma unroll
    for (int c = 0; c < 2; ++c) {
      int row = w * 16 + sr + c * 8;
      g2lds16((const char*)Bt + ((size_t)(n0 + row) * K + k0) * 2 + scb,
              (char*)lB + w * 2048 + c * 1024);
    }
    __syncthreads();
#pragma unroll
    for (int kc = 0; kc < 2; ++kc) {
      bf16x8 af[MI], bfr[2];
#pragma unroll
      for (int i = 0; i < MI; ++i)
        af[i] = *(const bf16x8*)((const char*)lA + (wm + i * 16 + l15) * 128 + kc * 64 + lg * 16);
#pragma unroll
      for (int j = 0; j < 2; ++j)
        bfr[j] = *(const bf16x8*)((const char*)lB + (wn + j * 16 + l15) * 128 + kc * 64 + lg * 16);
#pragma unroll
      for (int i = 0; i < MI; ++i)
#pragma unroll
        for (int j = 0; j < 2; ++j)
          acc[i][j] = mfma16(af[i], bfr[j], acc[i][j]);
    }
    __syncthreads();
  }
#pragma unroll
  for (int i = 0; i < MI; ++i) {
#pragma unroll
    for (int j = 0; j < 2; ++j) {
      int col = n0 + wn + j * 16 + l15;
      int row0 = m0 + wm + i * 16 + lg * 4;
      float vals[4];
#pragma unroll
      for (int r = 0; r < 4; ++r) vals[r] = acc[i][j][r] + bias[col];
      if (mode == 6) {
        int sel = col >> 9, c5 = col & 511;
        if (sel == 2) {
          int hh = c5 >> 6, dd = c5 & 63, bb = row0 >> 11, nn = row0 & 2047;
          u16x4 pk;
#pragma unroll
          for (int r = 0; r < 4; ++r) pk[r] = f2bs(vals[r]);
          *(u16x4*)(vtout + (((size_t)(bb * 8 + hh) * 64 + dd) * 2048 + nn)) = pk;
        } else {
#pragma unroll
          for (int r = 0; r < 4; ++r) {
            size_t idx = (size_t)(row0 + r) * 512 + c5;
            if (sel == 0) outh[idx] = f2bs(vals[r] * 0.125f);
            else if (sel == 1) outh[2097152 + idx] = f2bs(vals[r]);
            else outf[idx] = bs2f(A[idx]) * (1.f / (1.f + __expf(-vals[r])));
          }
        }
      } else {
#pragma unroll
        for (int r = 0; r < 4; ++r) {
          size_t idx = (size_t)(row0 + r) * N + col;
          if (mode == 3) outf[idx] = vals[r] + add1[idx] + add2[idx];
          else if (mode == 4) outh[idx] = f2bs(0.5f * vals[r] * (1.f + erff(vals[r] * 0.70710678f)));
          else outf[idx] = vals[r] + add1[idx];
        }
      }
    }
  }
}

// ---------------- flash attention v15 (verified R16): fused bias + counted vmcnt ----------------
// = R15's attn14 + conflict-free lsB pitch (KSTR 20B, BPITCH 648B -> worst-case 2-way).
// LDS-staged K/V (XOR swizzle, double buffer), bias f32 read once, prefetched a full
// iteration ahead; s_waitcnt vmcnt(3) drains the 8 K/V stages leaving 3 bias loads in
// flight; lgkm-only barriers (vmcnt never drained in the loop). Static-max softmax,
// l via mfma(P,ones). grid 256, 8 waves = 8 heads, (512,1) -> no VGPR cap, no spill.
#define BPITCH 648
#define KSTR 20
__global__ __launch_bounds__(512, 1) void k_attn15(
    const unsigned short* __restrict__ q, const unsigned short* __restrict__ kk,
    const unsigned short* __restrict__ vt, const float* __restrict__ bias,
    const unsigned char* __restrict__ mask, unsigned short* __restrict__ ao) {
  __shared__ __align__(16) char lsK[2][32768];
  __shared__ __align__(16) char lsV[2][32768];
  __shared__ __align__(16) char lsB[2][16 * BPITCH];
  __shared__ __align__(16) unsigned short ls_p[8][16][36];

  int bid = blockIdx.x;
  int b = bid >> 7, qt = bid & 127;
  int q0 = qt * 16;
  int t = threadIdx.x, w = t >> 6, l = t & 63;
  int l15 = l & 15, lg = l >> 4;
  int h = w;

  bf16x8 qa0 = *(const bf16x8*)(q + ((size_t)(b * 2048 + q0 + l15) * 512 + h * 64 + lg * 8));
  bf16x8 qa1 = *(const bf16x8*)(q + ((size_t)(b * 2048 + q0 + l15) * 512 + h * 64 + 32 + lg * 8));

  union { bf16x8 v; unsigned short s[8]; } uo;
#pragma unroll
  for (int j = 0; j < 8; ++j) uo.s[j] = 0x3F80;  // bf16 1.0
  const bf16x8 vones = uo.v;

  f32x4 oacc[4] = {};
  f32x4 lacc = {};

  const char* kptr[4];
  char* kdst[4];
#pragma unroll
  for (int i = 0; i < 4; ++i) {
    int fi = t + i * 512;
    int row = fi >> 6;
    int colb = ((fi & 63) * 16) ^ ((row & 7) << 4);
    kptr[i] = (const char*)kk + ((size_t)(b * 2048 + row) * 512) * 2 + colb;
    kdst[i] = (char*)0 + (i * 512 + w * 64) * 16;
  }
  const char* vptr[4];
#pragma unroll
  for (int i = 0; i < 4; ++i) {
    int fi = t + i * 512;
    int rv = fi >> 2;
    int dv = rv & 63, hv = rv >> 6;
    int slot = (fi & 3) ^ (dv & 3);
    vptr[i] = (const char*)vt + (((size_t)(b * 8 + hv) * 64 + dv) * 2048 + slot * 8) * 2;
  }
  int qq = t >> 5, kc = t & 31;
  const float* bptr = bias + ((size_t)(b * 2048 + q0 + qq) * 2048 + kc) * 8;
  const unsigned char* mptr = mask + (size_t)(b * 2048 + q0 + qq) * 2048 + kc;
  char* bdst = (char*)0 + qq * BPITCH + kc * KSTR;
  const unsigned short BN = f2bs(-1e30f);

#define STAGEKV(buf, kb)                                                     \
  do {                                                                       \
    _Pragma("unroll") for (int i = 0; i < 4; ++i)                            \
        g2lds16(kptr[i] + (size_t)(kb) * 1024, lsK[buf] + (size_t)kdst[i]);  \
    _Pragma("unroll") for (int i = 0; i < 4; ++i)                            \
        g2lds16(vptr[i] + (size_t)(kb) * 2, lsV[buf] + (size_t)kdst[i]);     \
  } while (0)
#define LOADB(BA, BB, MB, kb)                                                \
  do {                                                                       \
    BA = *(const float4*)(bptr + (size_t)(kb) * 8);                          \
    BB = *(const float4*)(bptr + (size_t)(kb) * 8 + 4);                      \
    MB = mptr[kb];                                                           \
  } while (0)
#define WRITEB(buf, BA, BB, MB)                                              \
  do {                                                                       \
    unsigned d0, d1, d2, d3;                                                 \
    if (MB) {                                                                \
      d0 = d1 = d2 = d3 = ((unsigned)BN << 16) | BN;                         \
    } else {                                                                 \
      d0 = f2bs(BA.x) | ((unsigned)f2bs(BA.y) << 16);                        \
      d1 = f2bs(BA.z) | ((unsigned)f2bs(BA.w) << 16);                        \
      d2 = f2bs(BB.x) | ((unsigned)f2bs(BB.y) << 16);                        \
      d3 = f2bs(BB.z) | ((unsigned)f2bs(BB.w) << 16);                        \
    }                                                                        \
    unsigned* bp_ = (unsigned*)(lsB[buf] + (size_t)bdst);                    \
    bp_[0] = d0; bp_[1] = d1; bp_[2] = d2; bp_[3] = d3;                      \
  } while (0)
#define LDSK(buf, tt, kcc)                                                   \
  (*(const bf16x8*)(lsK[buf] + ((tt)*16 + l15) * 1024 +                      \
                    ((h * 128 + (kcc)*64 + lg * 16) ^ ((((tt)*16 + l15) & 7) << 4))))
#define LDSV(buf, dt)                                                        \
  (*(const bf16x8*)(lsV[buf] +                                               \
                    (((h * 64 + (dt)*16 + l15) * 4 +                         \
                      (lg ^ (((dt)*16 + l15) & 3))) * 16)))
#define COMPUTE(buf)                                                         \
  do {                                                                       \
    f32x4 sc0 = {}, sc1 = {};                                                \
    sc0 = mfma16(qa0, LDSK(buf, 0, 0), sc0);                                 \
    sc0 = mfma16(qa1, LDSK(buf, 0, 1), sc0);                                 \
    sc1 = mfma16(qa0, LDSK(buf, 1, 0), sc1);                                 \
    sc1 = mfma16(qa1, LDSK(buf, 1, 1), sc1);                                 \
    _Pragma("unroll") for (int r = 0; r < 4; ++r) {                          \
      int qr = lg * 4 + r;                                                   \
      float b0 = bs2f(*(const unsigned short*)(lsB[buf] + qr * BPITCH + l15 * KSTR + h * 2));        \
      float b1 = bs2f(*(const unsigned short*)(lsB[buf] + qr * BPITCH + (l15 + 16) * KSTR + h * 2)); \
      float p0 = __expf(sc0[r] + b0 - 8.0f);                                 \
      float p1 = __expf(sc1[r] + b1 - 8.0f);                                 \
      ls_p[w][qr][l15] = f2bs(p0);                                           \
      ls_p[w][qr][16 + l15] = f2bs(p1);                                      \
    }                                                                        \
    bf16x8 pa = *(const bf16x8*)&ls_p[w][l15][lg * 8];                       \
    oacc[0] = mfma16(pa, LDSV(buf, 0), oacc[0]);                             \
    oacc[1] = mfma16(pa, LDSV(buf, 1), oacc[1]);                             \
    oacc[2] = mfma16(pa, LDSV(buf, 2), oacc[2]);                             \
    oacc[3] = mfma16(pa, LDSV(buf, 3), oacc[3]);                             \
    lacc = mfma16(pa, vones, lacc);                                          \
  } while (0)

  float4 rA0, rA1, rB0, rB1;
  unsigned char mA, mB;
  LOADB(rA0, rA1, mA, 0);
  WRITEB(0, rA0, rA1, mA);
  LOADB(rB0, rB1, mB, 32);
  SB;
  STAGEKV(0, 0);
  SB;
  vm_guard3();
  barrier_lgkm();
  for (int it = 0; it < 64; it += 2) {
    int kb1 = (it + 1) * 32;
    int kb2 = (it + 2 < 64) ? (it + 2) * 32 : 0;
    int kb3 = (it + 3 < 64) ? (it + 3) * 32 : 0;
    SB;
    STAGEKV(1, kb1);
    SB;
    LOADB(rA0, rA1, mA, kb2);
    SB;
    COMPUTE(0);
    WRITEB(1, rB0, rB1, mB);
    vm_guard3();
    barrier_lgkm();
    SB;
    STAGEKV(0, kb2);
    SB;
    LOADB(rB0, rB1, mB, kb3);
    SB;
    COMPUTE(1);
    WRITEB(0, rA0, rA1, mA);
    vm_guard3();
    barrier_lgkm();
  }
#undef STAGEKV
#undef LOADB
#undef WRITEB
#undef LDSK
#undef LDSV
#undef COMPUTE

#pragma unroll
  for (int d = 0; d < 4; ++d)
#pragma unroll
    for (int r = 0; r < 4; ++r) {
      size_t row = (size_t)(b * 2048 + q0 + lg * 4 + r);
      ao[row * 512 + h * 64 + d * 16 + l15] = f2bs(oacc[d][r] / lacc[r]);
    }
}

extern "C" void kernel_launch(void* const* d_in, const int* in_sizes, int n_in,
                              void* d_out, int out_size, void* d_ws, size_t ws_size,
                              hipStream_t stream) {
  (void)in_sizes; (void)n_in; (void)out_size; (void)ws_size;
  const float* x = (const float*)d_in[0];
  const float* abias = (const float*)d_in[1];
  const unsigned char* amask = (const unsigned char*)d_in[2];
  const float* Wq = (const float*)d_in[3];
  const float* bq = (const float*)d_in[4];
  const float* Wk = (const float*)d_in[5];
  const float* bk = (const float*)d_in[6];
  const float* Wv = (const float*)d_in[7];
  const float* bv = (const float*)d_in[8];
  const float* Wg = (const float*)d_in[9];
  const float* bg = (const float*)d_in[10];
  const float* Wo = (const float*)d_in[11];
  const float* bo = (const float*)d_in[12];
  const float* ln1g = (const float*)d_in[13];
  const float* ln1b = (const float*)d_in[14];
  const float* ln2g = (const float*)d_in[15];
  const float* ln2b = (const float*)d_in[16];
  const float* W1 = (const float*)d_in[17];
  const float* b1 = (const float*)d_in[18];
  const float* W2 = (const float*)d_in[19];
  const float* b2 = (const float*)d_in[20];
  float* outp = (float*)d_out;

  char* ws = (char*)d_ws;
  const size_t MB = 1024 * 1024;

  unsigned short* qb = (unsigned short*)(ws + 0);          // 4MB [4096][512]
  unsigned short* kb = (unsigned short*)(ws + 4 * MB);     // 4MB
  unsigned short* ao = (unsigned short*)(ws + 8 * MB);     // 4MB
  unsigned short* y1 = (unsigned short*)(ws + 28 * MB);    // 4MB
  unsigned short* h1 = (unsigned short*)(ws + 0);          // 16MB FFN phase
  float* u = (float*)(ws + 32 * MB);                       // 8MB
  unsigned short* wcat = (unsigned short*)(ws + 40 * MB);  // 2MB
  unsigned short* wot = (unsigned short*)(ws + 42 * MB);   // 0.5MB
  unsigned short* w1t = (unsigned short*)(ws + 42 * MB + 512 * 1024);
  unsigned short* w2t = (unsigned short*)(ws + 44 * MB + 512 * 1024);
  float* bcat = (float*)(ws + 46 * MB + 512 * 1024);
  unsigned short* vtb = (unsigned short*)(ws + 48 * MB);   // 4MB [2][8][64][2048]
  float* x2 = (float*)d_out;

  // batched 512x512 weight transposes (Wq,Wk,Wv,Wg -> wcat planes; Wo -> wot)
  k_transw5<<<dim3(8, 8, 5), 256, 0, stream>>>(Wq, Wk, Wv, Wg, Wo, wcat, wot);
  k_transw<<<dim3(8, 32), 256, 0, stream>>>(W1, w1t, 512, 2048);
  k_transw<<<dim3(32, 8), 256, 0, stream>>>(W2, w2t, 2048, 512);
  k_bcat<<<8, 256, 0, stream>>>(bq, bk, bv, bg, bcat);

  k_ln<<<4096, 256, 0, stream>>>(x, ln1g, ln1b, y1);
  k_gemm<128><<<dim3(32, 32), 256, 0, stream>>>(y1, wcat, bcat, 4096, 2048, 512, 6,
                                                u, qb, nullptr, nullptr, vtb);
  k_attn15<<<256, 512, 0, stream>>>(qb, kb, vtb, abias, amask, ao);
  k_gemm<64><<<dim3(64, 8), 256, 0, stream>>>(ao, wot, bo, 4096, 512, 512, 3,
                                              x2, nullptr, u, x, nullptr);
  k_ln<<<4096, 256, 0, stream>>>(x2, ln2g, ln2b, y1);
  k_gemm<128><<<dim3(32, 32), 256, 0, stream>>>(y1, w1t, b1, 4096, 2048, 512, 4,
                                                nullptr, h1, nullptr, nullptr, nullptr);
  k_gemm<64><<<dim3(64, 8), 256, 0, stream>>>(h1, w2t, b2, 4096, 512, 2048, 5,
                                              outp, nullptr, x2, nullptr, nullptr);
}

// Round 20
// 257.372 us; speedup vs baseline: 1.3079x; 1.0021x over previous
//
#include <hip/hip_runtime.h>
#include <hip/hip_bf16.h>

#define DI __device__ __forceinline__

typedef __attribute__((ext_vector_type(8))) __bf16 bf16x8;
typedef __attribute__((ext_vector_type(4))) float f32x4;
typedef __attribute__((ext_vector_type(4))) unsigned short u16x4;
typedef __attribute__((ext_vector_type(8))) unsigned short u16x8;

DI unsigned short f2bs(float f) {
  __hip_bfloat16 h = __float2bfloat16(f);
  return __builtin_bit_cast(unsigned short, h);
}
DI float bs2f(unsigned short s) {
  return __bfloat162float(__builtin_bit_cast(__hip_bfloat16, s));
}
DI f32x4 mfma16(bf16x8 a, bf16x8 b, f32x4 c) {
  return __builtin_amdgcn_mfma_f32_16x16x32_bf16(a, b, c, 0, 0, 0);
}
DI void g2lds16(const void* g, void* l) {
  __builtin_amdgcn_global_load_lds(
      (__attribute__((address_space(1))) void*)(unsigned long long)g,
      (__attribute__((address_space(3))) void*)l, 16, 0, 0);
}
#define SB __builtin_amdgcn_sched_barrier(0)
DI void barrier_lgkm() {
  asm volatile("s_waitcnt lgkmcnt(0)" ::: "memory");
  SB;
  __builtin_amdgcn_s_barrier();
  SB;
}
DI void vm_guard3() {
  SB;
  asm volatile("s_waitcnt vmcnt(3)" ::: "memory");
  SB;
}

// ---------------- batched weight transpose (5x 512x512) f32[K,N] -> bf16[N,K] ----------------
__global__ __launch_bounds__(256) void k_transw5(
    const float* __restrict__ W0, const float* __restrict__ W1,
    const float* __restrict__ W2, const float* __restrict__ W3,
    const float* __restrict__ W4, unsigned short* __restrict__ wcat,
    unsigned short* __restrict__ wot) {
  __shared__ float tile[64][65];
  int z = blockIdx.z;
  const float* W = z == 0 ? W0 : z == 1 ? W1 : z == 2 ? W2 : z == 3 ? W3 : W4;
  unsigned short* Wt = z < 4 ? wcat + (size_t)z * 512 * 512 : wot;
  int tk = blockIdx.x * 64, tn = blockIdx.y * 64;
  int t = threadIdx.x;
#pragma unroll
  for (int i = 0; i < 16; ++i) {
    int idx = t + i * 256;
    int r = idx >> 6, c = idx & 63;
    tile[r][c] = W[(size_t)(tk + r) * 512 + tn + c];
  }
  __syncthreads();
#pragma unroll
  for (int i = 0; i < 16; ++i) {
    int idx = t + i * 256;
    int n = idx >> 6, kk = idx & 63;
    Wt[(size_t)(tn + n) * 512 + tk + kk] = f2bs(tile[kk][n]);
  }
}

// ---------------- weight transpose f32[K,N] -> bf16[N,K] (generic) ----------------
__global__ __launch_bounds__(256) void k_transw(const float* __restrict__ W,
                                                unsigned short* __restrict__ Wt,
                                                int K, int N) {
  __shared__ float tile[64][65];
  int tk = blockIdx.x * 64, tn = blockIdx.y * 64;
  int t = threadIdx.x;
#pragma unroll
  for (int i = 0; i < 16; ++i) {
    int idx = t + i * 256;
    int r = idx >> 6, c = idx & 63;
    tile[r][c] = W[(size_t)(tk + r) * N + tn + c];
  }
  __syncthreads();
#pragma unroll
  for (int i = 0; i < 16; ++i) {
    int idx = t + i * 256;
    int n = idx >> 6, kk = idx & 63;
    Wt[(size_t)(tn + n) * K + tk + kk] = f2bs(tile[kk][n]);
  }
}

// ---------------- bias concat [bq|bk|bv|bg] -> bcat[2048] ----------------
__global__ __launch_bounds__(256) void k_bcat(const float* __restrict__ bq,
                                              const float* __restrict__ bk,
                                              const float* __restrict__ bv,
                                              const float* __restrict__ bg,
                                              float* __restrict__ bcat) {
  int t = blockIdx.x * 256 + threadIdx.x;
  const float* src = t < 512 ? bq : t < 1024 ? bk : t < 1536 ? bv : bg;
  bcat[t] = src[t & 511];
}

// ---------------- LayerNorm f32[rows,512] -> bf16 ----------------
__global__ __launch_bounds__(256) void k_ln(const float* __restrict__ x,
                                            const float* __restrict__ g,
                                            const float* __restrict__ b,
                                            unsigned short* __restrict__ y) {
  int row = blockIdx.x, t = threadIdx.x;
  const float* xr = x + (size_t)row * 512;
  float a0 = xr[t], a1 = xr[t + 256];
  float s1 = a0 + a1, s2 = a0 * a0 + a1 * a1;
#pragma unroll
  for (int o = 32; o > 0; o >>= 1) {
    s1 += __shfl_down(s1, o);
    s2 += __shfl_down(s2, o);
  }
  __shared__ float r1[4], r2[4], bc[2];
  int w = t >> 6, l = t & 63;
  if (l == 0) { r1[w] = s1; r2[w] = s2; }
  __syncthreads();
  if (t == 0) {
    float t1 = r1[0] + r1[1] + r1[2] + r1[3];
    float t2 = r2[0] + r2[1] + r2[2] + r2[3];
    float m = t1 / 512.f;
    float v = t2 / 512.f - m * m;
    bc[0] = m;
    bc[1] = rsqrtf(v + 1e-5f);
  }
  __syncthreads();
  float m = bc[0], inv = bc[1];
  y[(size_t)row * 512 + t] = f2bs((a0 - m) * inv * g[t] + b[t]);
  y[(size_t)row * 512 + t + 256] = f2bs((a1 - m) * inv * g[t + 256] + b[t + 256]);
}

// ---------------- GEMM: C[M,N] = A[M,K](bf16) * Bt[N,K]^T + bias (R15 config) ----------------
template <int BM>
__global__ __launch_bounds__(256) void k_gemm(
    const unsigned short* __restrict__ A, const unsigned short* __restrict__ Bt,
    const float* __restrict__ bias, int M, int N, int K, int mode,
    float* __restrict__ outf, unsigned short* __restrict__ outh,
    const float* __restrict__ add1, const float* __restrict__ add2,
    unsigned short* __restrict__ vtout) {
  constexpr int MI = BM / 32;
  __shared__ __align__(16) unsigned short lA[BM * 64];
  __shared__ __align__(16) unsigned short lB[64 * 64];
  int t = threadIdx.x, w = t >> 6, l = t & 63;
  int l15 = l & 15, lg = l >> 4;
  int m0 = blockIdx.x * BM, n0 = blockIdx.y * 64;
  int wm = (w >> 1) * (BM / 2), wn = (w & 1) * 32;
  f32x4 acc[MI][2] = {};
  int sr = l >> 3, scb = (l & 7) * 16;
  for (int k0 = 0; k0 < K; k0 += 64) {
#pragma unroll
    for (int c = 0; c < MI; ++c) {
      int row = w * (BM / 4) + sr + c * 8;
      g2lds16((const char*)A + ((size_t)(m0 + row) * K + k0) * 2 + scb,
              (char*)lA + w * (BM / 4) * 128 + c * 1024);
    }
#pragma unroll
    for (int c = 0; c < 2; ++c) {
      int row = w * 16 + sr + c * 8;
      g2lds16((const char*)Bt + ((size_t)(n0 + row) * K + k0) * 2 + scb,
              (char*)lB + w * 2048 + c * 1024);
    }
    __syncthreads();
#pragma unroll
    for (int kc = 0; kc < 2; ++kc) {
      bf16x8 af[MI], bfr[2];
#pragma unroll
      for (int i = 0; i < MI; ++i)
        af[i] = *(const bf16x8*)((const char*)lA + (wm + i * 16 + l15) * 128 + kc * 64 + lg * 16);
#pragma unroll
      for (int j = 0; j < 2; ++j)
        bfr[j] = *(const bf16x8*)((const char*)lB + (wn + j * 16 + l15) * 128 + kc * 64 + lg * 16);
#pragma unroll
      for (int i = 0; i < MI; ++i)
#pragma unroll
        for (int j = 0; j < 2; ++j)
          acc[i][j] = mfma16(af[i], bfr[j], acc[i][j]);
    }
    __syncthreads();
  }
#pragma unroll
  for (int i = 0; i < MI; ++i) {
#pragma unroll
    for (int j = 0; j < 2; ++j) {
      int col = n0 + wn + j * 16 + l15;
      int row0 = m0 + wm + i * 16 + lg * 4;
      float vals[4];
#pragma unroll
      for (int r = 0; r < 4; ++r) vals[r] = acc[i][j][r] + bias[col];
      if (mode == 6) {
        int sel = col >> 9, c5 = col & 511;
        if (sel == 2) {
          int hh = c5 >> 6, dd = c5 & 63, bb = row0 >> 11, nn = row0 & 2047;
          u16x4 pk;
#pragma unroll
          for (int r = 0; r < 4; ++r) pk[r] = f2bs(vals[r]);
          *(u16x4*)(vtout + (((size_t)(bb * 8 + hh) * 64 + dd) * 2048 + nn)) = pk;
        } else {
#pragma unroll
          for (int r = 0; r < 4; ++r) {
            size_t idx = (size_t)(row0 + r) * 512 + c5;
            if (sel == 0) outh[idx] = f2bs(vals[r] * 0.125f);
            else if (sel == 1) outh[2097152 + idx] = f2bs(vals[r]);
            else outf[idx] = bs2f(A[idx]) * (1.f / (1.f + __expf(-vals[r])));
          }
        }
      } else {
#pragma unroll
        for (int r = 0; r < 4; ++r) {
          size_t idx = (size_t)(row0 + r) * N + col;
          if (mode == 3) outf[idx] = vals[r] + add1[idx] + add2[idx];
          else if (mode == 4) outh[idx] = f2bs(0.5f * vals[r] * (1.f + erff(vals[r] * 0.70710678f)));
          else outf[idx] = vals[r] + add1[idx];
        }
      }
    }
  }
}

// ---------------- flash attention v16f: verified attn15 + XCD-parity b-map + setprio ----------------
// Two changes vs R19's verified kernel, both correctness-neutral:
// (1) b = bid&1, qt = bid>>1: each XCD (bid%8, single parity) serves ONE batch ->
//     hot K+V per XCD = 4MB = exactly L2; previously both batches (8MB > L2).
// (2) s_setprio(1) around the MFMA cluster (T5): scheduler favors the compute wave.
#define BPITCH 648
#define KSTR 20
__global__ __launch_bounds__(512, 1) void k_attn16f(
    const unsigned short* __restrict__ q, const unsigned short* __restrict__ kk,
    const unsigned short* __restrict__ vt, const float* __restrict__ bias,
    const unsigned char* __restrict__ mask, unsigned short* __restrict__ ao) {
  __shared__ __align__(16) char lsK[2][32768];
  __shared__ __align__(16) char lsV[2][32768];
  __shared__ __align__(16) char lsB[2][16 * BPITCH];
  __shared__ __align__(16) unsigned short ls_p[8][16][36];

  int bid = blockIdx.x;
  int b = bid & 1, qt = bid >> 1;   // XCD-parity batch mapping
  int q0 = qt * 16;
  int t = threadIdx.x, w = t >> 6, l = t & 63;
  int l15 = l & 15, lg = l >> 4;
  int h = w;

  bf16x8 qa0 = *(const bf16x8*)(q + ((size_t)(b * 2048 + q0 + l15) * 512 + h * 64 + lg * 8));
  bf16x8 qa1 = *(const bf16x8*)(q + ((size_t)(b * 2048 + q0 + l15) * 512 + h * 64 + 32 + lg * 8));

  union { bf16x8 v; unsigned short s[8]; } uo;
#pragma unroll
  for (int j = 0; j < 8; ++j) uo.s[j] = 0x3F80;  // bf16 1.0
  const bf16x8 vones = uo.v;

  f32x4 oacc[4] = {};
  f32x4 lacc = {};

  const char* kptr[4];
  char* kdst[4];
#pragma unroll
  for (int i = 0; i < 4; ++i) {
    int fi = t + i * 512;
    int row = fi >> 6;
    int colb = ((fi & 63) * 16) ^ ((row & 7) << 4);
    kptr[i] = (const char*)kk + ((size_t)(b * 2048 + row) * 512) * 2 + colb;
    kdst[i] = (char*)0 + (i * 512 + w * 64) * 16;
  }
  const char* vptr[4];
#pragma unroll
  for (int i = 0; i < 4; ++i) {
    int fi = t + i * 512;
    int rv = fi >> 2;
    int dv = rv & 63, hv = rv >> 6;
    int slot = (fi & 3) ^ (dv & 3);
    vptr[i] = (const char*)vt + (((size_t)(b * 8 + hv) * 64 + dv) * 2048 + slot * 8) * 2;
  }
  int qq = t >> 5, kc = t & 31;
  const float* bptr = bias + ((size_t)(b * 2048 + q0 + qq) * 2048 + kc) * 8;
  const unsigned char* mptr = mask + (size_t)(b * 2048 + q0 + qq) * 2048 + kc;
  char* bdst = (char*)0 + qq * BPITCH + kc * KSTR;
  const unsigned short BN = f2bs(-1e30f);

#define STAGEKV(buf, kb)                                                     \
  do {                                                                       \
    _Pragma("unroll") for (int i = 0; i < 4; ++i)                            \
        g2lds16(kptr[i] + (size_t)(kb) * 1024, lsK[buf] + (size_t)kdst[i]);  \
    _Pragma("unroll") for (int i = 0; i < 4; ++i)                            \
        g2lds16(vptr[i] + (size_t)(kb) * 2, lsV[buf] + (size_t)kdst[i]);     \
  } while (0)
#define LOADB(BA, BB, MB, kb)                                                \
  do {                                                                       \
    BA = *(const float4*)(bptr + (size_t)(kb) * 8);                          \
    BB = *(const float4*)(bptr + (size_t)(kb) * 8 + 4);                      \
    MB = mptr[kb];                                                           \
  } while (0)
#define WRITEB(buf, BA, BB, MB)                                              \
  do {                                                                       \
    unsigned d0, d1, d2, d3;                                                 \
    if (MB) {                                                                \
      d0 = d1 = d2 = d3 = ((unsigned)BN << 16) | BN;                         \
    } else {                                                                 \
      d0 = f2bs(BA.x) | ((unsigned)f2bs(BA.y) << 16);                        \
      d1 = f2bs(BA.z) | ((unsigned)f2bs(BA.w) << 16);                        \
      d2 = f2bs(BB.x) | ((unsigned)f2bs(BB.y) << 16);                        \
      d3 = f2bs(BB.z) | ((unsigned)f2bs(BB.w) << 16);                        \
    }                                                                        \
    unsigned* bp_ = (unsigned*)(lsB[buf] + (size_t)bdst);                    \
    bp_[0] = d0; bp_[1] = d1; bp_[2] = d2; bp_[3] = d3;                      \
  } while (0)
#define LDSK(buf, tt, kcc)                                                   \
  (*(const bf16x8*)(lsK[buf] + ((tt)*16 + l15) * 1024 +                      \
                    ((h * 128 + (kcc)*64 + lg * 16) ^ ((((tt)*16 + l15) & 7) << 4))))
#define LDSV(buf, dt)                                                        \
  (*(const bf16x8*)(lsV[buf] +                                               \
                    (((h * 64 + (dt)*16 + l15) * 4 +                         \
                      (lg ^ (((dt)*16 + l15) & 3))) * 16)))
#define COMPUTE(buf)                                                         \
  do {                                                                       \
    f32x4 sc0 = {}, sc1 = {};                                                \
    __builtin_amdgcn_s_setprio(1);                                           \
    sc0 = mfma16(qa0, LDSK(buf, 0, 0), sc0);                                 \
    sc0 = mfma16(qa1, LDSK(buf, 0, 1), sc0);                                 \
    sc1 = mfma16(qa0, LDSK(buf, 1, 0), sc1);                                 \
    sc1 = mfma16(qa1, LDSK(buf, 1, 1), sc1);                                 \
    __builtin_amdgcn_s_setprio(0);                                           \
    _Pragma("unroll") for (int r = 0; r < 4; ++r) {                          \
      int qr = lg * 4 + r;                                                   \
      float b0 = bs2f(*(const unsigned short*)(lsB[buf] + qr * BPITCH + l15 * KSTR + h * 2));        \
      float b1 = bs2f(*(const unsigned short*)(lsB[buf] + qr * BPITCH + (l15 + 16) * KSTR + h * 2)); \
      float p0 = __expf(sc0[r] + b0 - 8.0f);                                 \
      float p1 = __expf(sc1[r] + b1 - 8.0f);                                 \
      ls_p[w][qr][l15] = f2bs(p0);                                           \
      ls_p[w][qr][16 + l15] = f2bs(p1);                                      \
    }                                                                        \
    bf16x8 pa = *(const bf16x8*)&ls_p[w][l15][lg * 8];                       \
    __builtin_amdgcn_s_setprio(1);                                           \
    oacc[0] = mfma16(pa, LDSV(buf, 0), oacc[0]);                             \
    oacc[1] = mfma16(pa, LDSV(buf, 1), oacc[1]);                             \
    oacc[2] = mfma16(pa, LDSV(buf, 2), oacc[2]);                             \
    oacc[3] = mfma16(pa, LDSV(buf, 3), oacc[3]);                             \
    lacc = mfma16(pa, vones, lacc);                                          \
    __builtin_amdgcn_s_setprio(0);                                           \
  } while (0)

  float4 rA0, rA1, rB0, rB1;
  unsigned char mA, mB;
  LOADB(rA0, rA1, mA, 0);
  WRITEB(0, rA0, rA1, mA);
  LOADB(rB0, rB1, mB, 32);
  SB;
  STAGEKV(0, 0);
  SB;
  vm_guard3();
  barrier_lgkm();
  for (int it = 0; it < 64; it += 2) {
    int kb1 = (it + 1) * 32;
    int kb2 = (it + 2 < 64) ? (it + 2) * 32 : 0;
    int kb3 = (it + 3 < 64) ? (it + 3) * 32 : 0;
    SB;
    STAGEKV(1, kb1);
    SB;
    LOADB(rA0, rA1, mA, kb2);
    SB;
    COMPUTE(0);
    WRITEB(1, rB0, rB1, mB);
    vm_guard3();
    barrier_lgkm();
    SB;
    STAGEKV(0, kb2);
    SB;
    LOADB(rB0, rB1, mB, kb3);
    SB;
    COMPUTE(1);
    WRITEB(0, rA0, rA1, mA);
    vm_guard3();
    barrier_lgkm();
  }
#undef STAGEKV
#undef LOADB
#undef WRITEB
#undef LDSK
#undef LDSV
#undef COMPUTE

#pragma unroll
  for (int d = 0; d < 4; ++d)
#pragma unroll
    for (int r = 0; r < 4; ++r) {
      size_t row = (size_t)(b * 2048 + q0 + lg * 4 + r);
      ao[row * 512 + h * 64 + d * 16 + l15] = f2bs(oacc[d][r] / lacc[r]);
    }
}

extern "C" void kernel_launch(void* const* d_in, const int* in_sizes, int n_in,
                              void* d_out, int out_size, void* d_ws, size_t ws_size,
                              hipStream_t stream) {
  (void)in_sizes; (void)n_in; (void)out_size; (void)ws_size;
  const float* x = (const float*)d_in[0];
  const float* abias = (const float*)d_in[1];
  const unsigned char* amask = (const unsigned char*)d_in[2];
  const float* Wq = (const float*)d_in[3];
  const float* bq = (const float*)d_in[4];
  const float* Wk = (const float*)d_in[5];
  const float* bk = (const float*)d_in[6];
  const float* Wv = (const float*)d_in[7];
  const float* bv = (const float*)d_in[8];
  const float* Wg = (const float*)d_in[9];
  const float* bg = (const float*)d_in[10];
  const float* Wo = (const float*)d_in[11];
  const float* bo = (const float*)d_in[12];
  const float* ln1g = (const float*)d_in[13];
  const float* ln1b = (const float*)d_in[14];
  const float* ln2g = (const float*)d_in[15];
  const float* ln2b = (const float*)d_in[16];
  const float* W1 = (const float*)d_in[17];
  const float* b1 = (const float*)d_in[18];
  const float* W2 = (const float*)d_in[19];
  const float* b2 = (const float*)d_in[20];
  float* outp = (float*)d_out;

  char* ws = (char*)d_ws;
  const size_t MB = 1024 * 1024;

  unsigned short* qb = (unsigned short*)(ws + 0);          // 4MB [4096][512]
  unsigned short* kb = (unsigned short*)(ws + 4 * MB);     // 4MB
  unsigned short* ao = (unsigned short*)(ws + 8 * MB);     // 4MB
  unsigned short* y1 = (unsigned short*)(ws + 28 * MB);    // 4MB
  unsigned short* h1 = (unsigned short*)(ws + 0);          // 16MB FFN phase
  float* u = (float*)(ws + 32 * MB);                       // 8MB
  unsigned short* wcat = (unsigned short*)(ws + 40 * MB);  // 2MB
  unsigned short* wot = (unsigned short*)(ws + 42 * MB);   // 0.5MB
  unsigned short* w1t = (unsigned short*)(ws + 42 * MB + 512 * 1024);
  unsigned short* w2t = (unsigned short*)(ws + 44 * MB + 512 * 1024);
  float* bcat = (float*)(ws + 46 * MB + 512 * 1024);
  unsigned short* vtb = (unsigned short*)(ws + 48 * MB);   // 4MB [2][8][64][2048]
  float* x2 = (float*)d_out;

  k_transw5<<<dim3(8, 8, 5), 256, 0, stream>>>(Wq, Wk, Wv, Wg, Wo, wcat, wot);
  k_transw<<<dim3(8, 32), 256, 0, stream>>>(W1, w1t, 512, 2048);
  k_transw<<<dim3(32, 8), 256, 0, stream>>>(W2, w2t, 2048, 512);
  k_bcat<<<8, 256, 0, stream>>>(bq, bk, bv, bg, bcat);

  k_ln<<<4096, 256, 0, stream>>>(x, ln1g, ln1b, y1);
  k_gemm<128><<<dim3(32, 32), 256, 0, stream>>>(y1, wcat, bcat, 4096, 2048, 512, 6,
                                                u, qb, nullptr, nullptr, vtb);
  k_attn16f<<<256, 512, 0, stream>>>(qb, kb, vtb, abias, amask, ao);
  k_gemm<64><<<dim3(64, 8), 256, 0, stream>>>(ao, wot, bo, 4096, 512, 512, 3,
                                              x2, nullptr, u, x, nullptr);
  k_ln<<<4096, 256, 0, stream>>>(x2, ln2g, ln2b, y1);
  k_gemm<128><<<dim3(32, 32), 256, 0, stream>>>(y1, w1t, b1, 4096, 2048, 512, 4,
                                                nullptr, h1, nullptr, nullptr, nullptr);
  k_gemm<64><<<dim3(64, 8), 256, 0, stream>>>(h1, w2t, b2, 4096, 512, 2048, 5,
                                              outp, nullptr, x2, nullptr, nullptr);
}

// Round 21
// 255.303 us; speedup vs baseline: 1.3185x; 1.0081x over previous
//
#include <hip/hip_runtime.h>
#include <hip/hip_bf16.h>

#define DI __device__ __forceinline__

typedef __attribute__((ext_vector_type(8))) __bf16 bf16x8;
typedef __attribute__((ext_vector_type(4))) float f32x4;
typedef __attribute__((ext_vector_type(4))) unsigned short u16x4;
typedef __attribute__((ext_vector_type(8))) unsigned short u16x8;

DI unsigned short f2bs(float f) {
  __hip_bfloat16 h = __float2bfloat16(f);
  return __builtin_bit_cast(unsigned short, h);
}
DI float bs2f(unsigned short s) {
  return __bfloat162float(__builtin_bit_cast(__hip_bfloat16, s));
}
DI f32x4 mfma16(bf16x8 a, bf16x8 b, f32x4 c) {
  return __builtin_amdgcn_mfma_f32_16x16x32_bf16(a, b, c, 0, 0, 0);
}
DI void g2lds16(const void* g, void* l) {
  __builtin_amdgcn_global_load_lds(
      (__attribute__((address_space(1))) void*)(unsigned long long)g,
      (__attribute__((address_space(3))) void*)l, 16, 0, 0);
}
#define SB __builtin_amdgcn_sched_barrier(0)
DI void barrier_lgkm() {
  asm volatile("s_waitcnt lgkmcnt(0)" ::: "memory");
  SB;
  __builtin_amdgcn_s_barrier();
  SB;
}
DI void vm_guard3() {
  SB;
  asm volatile("s_waitcnt vmcnt(3)" ::: "memory");
  SB;
}

// ---------------- batched weight transpose (5x 512x512) + bias concat ----------------
// z=0..4: transpose W_z f32[512,512] -> bf16[N,K] (wcat planes / wot).
// z=5 (first 8 blocks): bcat[t] = concat(bq,bk,bv,bg).
__global__ __launch_bounds__(256) void k_transw5(
    const float* __restrict__ W0, const float* __restrict__ W1,
    const float* __restrict__ W2, const float* __restrict__ W3,
    const float* __restrict__ W4, unsigned short* __restrict__ wcat,
    unsigned short* __restrict__ wot, const float* __restrict__ bq,
    const float* __restrict__ bk, const float* __restrict__ bv,
    const float* __restrict__ bg, float* __restrict__ bcat) {
  int z = blockIdx.z;
  int t = threadIdx.x;
  if (z == 5) {
    if (blockIdx.y == 0 && blockIdx.x < 8) {
      int idx = blockIdx.x * 256 + t;
      const float* src = idx < 512 ? bq : idx < 1024 ? bk : idx < 1536 ? bv : bg;
      bcat[idx] = src[idx & 511];
    }
    return;
  }
  __shared__ float tile[64][65];
  const float* W = z == 0 ? W0 : z == 1 ? W1 : z == 2 ? W2 : z == 3 ? W3 : W4;
  unsigned short* Wt = z < 4 ? wcat + (size_t)z * 512 * 512 : wot;
  int tk = blockIdx.x * 64, tn = blockIdx.y * 64;
#pragma unroll
  for (int i = 0; i < 16; ++i) {
    int idx = t + i * 256;
    int r = idx >> 6, c = idx & 63;
    tile[r][c] = W[(size_t)(tk + r) * 512 + tn + c];
  }
  __syncthreads();
#pragma unroll
  for (int i = 0; i < 16; ++i) {
    int idx = t + i * 256;
    int n = idx >> 6, kk = idx & 63;
    Wt[(size_t)(tn + n) * 512 + tk + kk] = f2bs(tile[kk][n]);
  }
}

// ---------------- weight transpose f32[K,N] -> bf16[N,K] (generic) ----------------
__global__ __launch_bounds__(256) void k_transw(const float* __restrict__ W,
                                                unsigned short* __restrict__ Wt,
                                                int K, int N) {
  __shared__ float tile[64][65];
  int tk = blockIdx.x * 64, tn = blockIdx.y * 64;
  int t = threadIdx.x;
#pragma unroll
  for (int i = 0; i < 16; ++i) {
    int idx = t + i * 256;
    int r = idx >> 6, c = idx & 63;
    tile[r][c] = W[(size_t)(tk + r) * N + tn + c];
  }
  __syncthreads();
#pragma unroll
  for (int i = 0; i < 16; ++i) {
    int idx = t + i * 256;
    int n = idx >> 6, kk = idx & 63;
    Wt[(size_t)(tn + n) * K + tk + kk] = f2bs(tile[kk][n]);
  }
}

// ---------------- LayerNorm f32[rows,512] -> bf16 ----------------
__global__ __launch_bounds__(256) void k_ln(const float* __restrict__ x,
                                            const float* __restrict__ g,
                                            const float* __restrict__ b,
                                            unsigned short* __restrict__ y) {
  int row = blockIdx.x, t = threadIdx.x;
  const float* xr = x + (size_t)row * 512;
  float a0 = xr[t], a1 = xr[t + 256];
  float s1 = a0 + a1, s2 = a0 * a0 + a1 * a1;
#pragma unroll
  for (int o = 32; o > 0; o >>= 1) {
    s1 += __shfl_down(s1, o);
    s2 += __shfl_down(s2, o);
  }
  __shared__ float r1[4], r2[4], bc[2];
  int w = t >> 6, l = t & 63;
  if (l == 0) { r1[w] = s1; r2[w] = s2; }
  __syncthreads();
  if (t == 0) {
    float t1 = r1[0] + r1[1] + r1[2] + r1[3];
    float t2 = r2[0] + r2[1] + r2[2] + r2[3];
    float m = t1 / 512.f;
    float v = t2 / 512.f - m * m;
    bc[0] = m;
    bc[1] = rsqrtf(v + 1e-5f);
  }
  __syncthreads();
  float m = bc[0], inv = bc[1];
  y[(size_t)row * 512 + t] = f2bs((a0 - m) * inv * g[t] + b[t]);
  y[(size_t)row * 512 + t + 256] = f2bs((a1 - m) * inv * g[t + 256] + b[t + 256]);
}

// ---------------- GEMM: C[M,N] = A[M,K](bf16) * Bt[N,K]^T + bias (R15 config) ----------------
template <int BM>
__global__ __launch_bounds__(256) void k_gemm(
    const unsigned short* __restrict__ A, const unsigned short* __restrict__ Bt,
    const float* __restrict__ bias, int M, int N, int K, int mode,
    float* __restrict__ outf, unsigned short* __restrict__ outh,
    const float* __restrict__ add1, const float* __restrict__ add2,
    unsigned short* __restrict__ vtout) {
  constexpr int MI = BM / 32;
  __shared__ __align__(16) unsigned short lA[BM * 64];
  __shared__ __align__(16) unsigned short lB[64 * 64];
  int t = threadIdx.x, w = t >> 6, l = t & 63;
  int l15 = l & 15, lg = l >> 4;
  int m0 = blockIdx.x * BM, n0 = blockIdx.y * 64;
  int wm = (w >> 1) * (BM / 2), wn = (w & 1) * 32;
  f32x4 acc[MI][2] = {};
  int sr = l >> 3, scb = (l & 7) * 16;
  for (int k0 = 0; k0 < K; k0 += 64) {
#pragma unroll
    for (int c = 0; c < MI; ++c) {
      int row = w * (BM / 4) + sr + c * 8;
      g2lds16((const char*)A + ((size_t)(m0 + row) * K + k0) * 2 + scb,
              (char*)lA + w * (BM / 4) * 128 + c * 1024);
    }
#pragma unroll
    for (int c = 0; c < 2; ++c) {
      int row = w * 16 + sr + c * 8;
      g2lds16((const char*)Bt + ((size_t)(n0 + row) * K + k0) * 2 + scb,
              (char*)lB + w * 2048 + c * 1024);
    }
    __syncthreads();
#pragma unroll
    for (int kc = 0; kc < 2; ++kc) {
      bf16x8 af[MI], bfr[2];
#pragma unroll
      for (int i = 0; i < MI; ++i)
        af[i] = *(const bf16x8*)((const char*)lA + (wm + i * 16 + l15) * 128 + kc * 64 + lg * 16);
#pragma unroll
      for (int j = 0; j < 2; ++j)
        bfr[j] = *(const bf16x8*)((const char*)lB + (wn + j * 16 + l15) * 128 + kc * 64 + lg * 16);
#pragma unroll
      for (int i = 0; i < MI; ++i)
#pragma unroll
        for (int j = 0; j < 2; ++j)
          acc[i][j] = mfma16(af[i], bfr[j], acc[i][j]);
    }
    __syncthreads();
  }
#pragma unroll
  for (int i = 0; i < MI; ++i) {
#pragma unroll
    for (int j = 0; j < 2; ++j) {
      int col = n0 + wn + j * 16 + l15;
      int row0 = m0 + wm + i * 16 + lg * 4;
      float vals[4];
#pragma unroll
      for (int r = 0; r < 4; ++r) vals[r] = acc[i][j][r] + bias[col];
      if (mode == 6) {
        int sel = col >> 9, c5 = col & 511;
        if (sel == 2) {
          int hh = c5 >> 6, dd = c5 & 63, bb = row0 >> 11, nn = row0 & 2047;
          u16x4 pk;
#pragma unroll
          for (int r = 0; r < 4; ++r) pk[r] = f2bs(vals[r]);
          *(u16x4*)(vtout + (((size_t)(bb * 8 + hh) * 64 + dd) * 2048 + nn)) = pk;
        } else {
#pragma unroll
          for (int r = 0; r < 4; ++r) {
            size_t idx = (size_t)(row0 + r) * 512 + c5;
            if (sel == 0) outh[idx] = f2bs(vals[r] * 0.125f);
            else if (sel == 1) outh[2097152 + idx] = f2bs(vals[r]);
            else outf[idx] = bs2f(A[idx]) * (1.f / (1.f + __expf(-vals[r])));
          }
        }
      } else {
#pragma unroll
        for (int r = 0; r < 4; ++r) {
          size_t idx = (size_t)(row0 + r) * N + col;
          if (mode == 3) outf[idx] = vals[r] + add1[idx] + add2[idx];
          else if (mode == 4) outh[idx] = f2bs(0.5f * vals[r] * (1.f + erff(vals[r] * 0.70710678f)));
          else outf[idx] = vals[r] + add1[idx];
        }
      }
    }
  }
}

// ---------------- flash attention (verified R20): fused bias, counted vmcnt, XCD parity ----------------
#define BPITCH 648
#define KSTR 20
__global__ __launch_bounds__(512, 1) void k_attn16f(
    const unsigned short* __restrict__ q, const unsigned short* __restrict__ kk,
    const unsigned short* __restrict__ vt, const float* __restrict__ bias,
    const unsigned char* __restrict__ mask, unsigned short* __restrict__ ao) {
  __shared__ __align__(16) char lsK[2][32768];
  __shared__ __align__(16) char lsV[2][32768];
  __shared__ __align__(16) char lsB[2][16 * BPITCH];
  __shared__ __align__(16) unsigned short ls_p[8][16][36];

  int bid = blockIdx.x;
  int b = bid & 1, qt = bid >> 1;   // XCD-parity batch mapping (one batch per XCD L2)
  int q0 = qt * 16;
  int t = threadIdx.x, w = t >> 6, l = t & 63;
  int l15 = l & 15, lg = l >> 4;
  int h = w;

  bf16x8 qa0 = *(const bf16x8*)(q + ((size_t)(b * 2048 + q0 + l15) * 512 + h * 64 + lg * 8));
  bf16x8 qa1 = *(const bf16x8*)(q + ((size_t)(b * 2048 + q0 + l15) * 512 + h * 64 + 32 + lg * 8));

  union { bf16x8 v; unsigned short s[8]; } uo;
#pragma unroll
  for (int j = 0; j < 8; ++j) uo.s[j] = 0x3F80;  // bf16 1.0
  const bf16x8 vones = uo.v;

  f32x4 oacc[4] = {};
  f32x4 lacc = {};

  const char* kptr[4];
  char* kdst[4];
#pragma unroll
  for (int i = 0; i < 4; ++i) {
    int fi = t + i * 512;
    int row = fi >> 6;
    int colb = ((fi & 63) * 16) ^ ((row & 7) << 4);
    kptr[i] = (const char*)kk + ((size_t)(b * 2048 + row) * 512) * 2 + colb;
    kdst[i] = (char*)0 + (i * 512 + w * 64) * 16;
  }
  const char* vptr[4];
#pragma unroll
  for (int i = 0; i < 4; ++i) {
    int fi = t + i * 512;
    int rv = fi >> 2;
    int dv = rv & 63, hv = rv >> 6;
    int slot = (fi & 3) ^ (dv & 3);
    vptr[i] = (const char*)vt + (((size_t)(b * 8 + hv) * 64 + dv) * 2048 + slot * 8) * 2;
  }
  int qq = t >> 5, kc = t & 31;
  const float* bptr = bias + ((size_t)(b * 2048 + q0 + qq) * 2048 + kc) * 8;
  const unsigned char* mptr = mask + (size_t)(b * 2048 + q0 + qq) * 2048 + kc;
  char* bdst = (char*)0 + qq * BPITCH + kc * KSTR;
  const unsigned short BN = f2bs(-1e30f);

#define STAGEKV(buf, kb)                                                     \
  do {                                                                       \
    _Pragma("unroll") for (int i = 0; i < 4; ++i)                            \
        g2lds16(kptr[i] + (size_t)(kb) * 1024, lsK[buf] + (size_t)kdst[i]);  \
    _Pragma("unroll") for (int i = 0; i < 4; ++i)                            \
        g2lds16(vptr[i] + (size_t)(kb) * 2, lsV[buf] + (size_t)kdst[i]);     \
  } while (0)
#define LOADB(BA, BB, MB, kb)                                                \
  do {                                                                       \
    BA = *(const float4*)(bptr + (size_t)(kb) * 8);                          \
    BB = *(const float4*)(bptr + (size_t)(kb) * 8 + 4);                      \
    MB = mptr[kb];                                                           \
  } while (0)
#define WRITEB(buf, BA, BB, MB)                                              \
  do {                                                                       \
    unsigned d0, d1, d2, d3;                                                 \
    if (MB) {                                                                \
      d0 = d1 = d2 = d3 = ((unsigned)BN << 16) | BN;                         \
    } else {                                                                 \
      d0 = f2bs(BA.x) | ((unsigned)f2bs(BA.y) << 16);                        \
      d1 = f2bs(BA.z) | ((unsigned)f2bs(BA.w) << 16);                        \
      d2 = f2bs(BB.x) | ((unsigned)f2bs(BB.y) << 16);                        \
      d3 = f2bs(BB.z) | ((unsigned)f2bs(BB.w) << 16);                        \
    }                                                                        \
    unsigned* bp_ = (unsigned*)(lsB[buf] + (size_t)bdst);                    \
    bp_[0] = d0; bp_[1] = d1; bp_[2] = d2; bp_[3] = d3;                      \
  } while (0)
#define LDSK(buf, tt, kcc)                                                   \
  (*(const bf16x8*)(lsK[buf] + ((tt)*16 + l15) * 1024 +                      \
                    ((h * 128 + (kcc)*64 + lg * 16) ^ ((((tt)*16 + l15) & 7) << 4))))
#define LDSV(buf, dt)                                                        \
  (*(const bf16x8*)(lsV[buf] +                                               \
                    (((h * 64 + (dt)*16 + l15) * 4 +                         \
                      (lg ^ (((dt)*16 + l15) & 3))) * 16)))
#define COMPUTE(buf)                                                         \
  do {                                                                       \
    f32x4 sc0 = {}, sc1 = {};                                                \
    __builtin_amdgcn_s_setprio(1);                                           \
    sc0 = mfma16(qa0, LDSK(buf, 0, 0), sc0);                                 \
    sc0 = mfma16(qa1, LDSK(buf, 0, 1), sc0);                                 \
    sc1 = mfma16(qa0, LDSK(buf, 1, 0), sc1);                                 \
    sc1 = mfma16(qa1, LDSK(buf, 1, 1), sc1);                                 \
    __builtin_amdgcn_s_setprio(0);                                           \
    _Pragma("unroll") for (int r = 0; r < 4; ++r) {                          \
      int qr = lg * 4 + r;                                                   \
      float b0 = bs2f(*(const unsigned short*)(lsB[buf] + qr * BPITCH + l15 * KSTR + h * 2));        \
      float b1 = bs2f(*(const unsigned short*)(lsB[buf] + qr * BPITCH + (l15 + 16) * KSTR + h * 2)); \
      float p0 = __expf(sc0[r] + b0 - 8.0f);                                 \
      float p1 = __expf(sc1[r] + b1 - 8.0f);                                 \
      ls_p[w][qr][l15] = f2bs(p0);                                           \
      ls_p[w][qr][16 + l15] = f2bs(p1);                                      \
    }                                                                        \
    bf16x8 pa = *(const bf16x8*)&ls_p[w][l15][lg * 8];                       \
    __builtin_amdgcn_s_setprio(1);                                           \
    oacc[0] = mfma16(pa, LDSV(buf, 0), oacc[0]);                             \
    oacc[1] = mfma16(pa, LDSV(buf, 1), oacc[1]);                             \
    oacc[2] = mfma16(pa, LDSV(buf, 2), oacc[2]);                             \
    oacc[3] = mfma16(pa, LDSV(buf, 3), oacc[3]);                             \
    lacc = mfma16(pa, vones, lacc);                                          \
    __builtin_amdgcn_s_setprio(0);                                           \
  } while (0)

  float4 rA0, rA1, rB0, rB1;
  unsigned char mA, mB;
  LOADB(rA0, rA1, mA, 0);
  WRITEB(0, rA0, rA1, mA);
  LOADB(rB0, rB1, mB, 32);
  SB;
  STAGEKV(0, 0);
  SB;
  vm_guard3();
  barrier_lgkm();
  for (int it = 0; it < 64; it += 2) {
    int kb1 = (it + 1) * 32;
    int kb2 = (it + 2 < 64) ? (it + 2) * 32 : 0;
    int kb3 = (it + 3 < 64) ? (it + 3) * 32 : 0;
    SB;
    STAGEKV(1, kb1);
    SB;
    LOADB(rA0, rA1, mA, kb2);
    SB;
    COMPUTE(0);
    WRITEB(1, rB0, rB1, mB);
    vm_guard3();
    barrier_lgkm();
    SB;
    STAGEKV(0, kb2);
    SB;
    LOADB(rB0, rB1, mB, kb3);
    SB;
    COMPUTE(1);
    WRITEB(0, rA0, rA1, mA);
    vm_guard3();
    barrier_lgkm();
  }
#undef STAGEKV
#undef LOADB
#undef WRITEB
#undef LDSK
#undef LDSV
#undef COMPUTE

#pragma unroll
  for (int d = 0; d < 4; ++d)
#pragma unroll
    for (int r = 0; r < 4; ++r) {
      size_t row = (size_t)(b * 2048 + q0 + lg * 4 + r);
      ao[row * 512 + h * 64 + d * 16 + l15] = f2bs(oacc[d][r] / lacc[r]);
    }
}

extern "C" void kernel_launch(void* const* d_in, const int* in_sizes, int n_in,
                              void* d_out, int out_size, void* d_ws, size_t ws_size,
                              hipStream_t stream) {
  (void)in_sizes; (void)n_in; (void)out_size; (void)ws_size;
  const float* x = (const float*)d_in[0];
  const float* abias = (const float*)d_in[1];
  const unsigned char* amask = (const unsigned char*)d_in[2];
  const float* Wq = (const float*)d_in[3];
  const float* bq = (const float*)d_in[4];
  const float* Wk = (const float*)d_in[5];
  const float* bk = (const float*)d_in[6];
  const float* Wv = (const float*)d_in[7];
  const float* bv = (const float*)d_in[8];
  const float* Wg = (const float*)d_in[9];
  const float* bg = (const float*)d_in[10];
  const float* Wo = (const float*)d_in[11];
  const float* bo = (const float*)d_in[12];
  const float* ln1g = (const float*)d_in[13];
  const float* ln1b = (const float*)d_in[14];
  const float* ln2g = (const float*)d_in[15];
  const float* ln2b = (const float*)d_in[16];
  const float* W1 = (const float*)d_in[17];
  const float* b1 = (const float*)d_in[18];
  const float* W2 = (const float*)d_in[19];
  const float* b2 = (const float*)d_in[20];
  float* outp = (float*)d_out;

  char* ws = (char*)d_ws;
  const size_t MB = 1024 * 1024;

  unsigned short* qb = (unsigned short*)(ws + 0);          // 4MB [4096][512]
  unsigned short* kb = (unsigned short*)(ws + 4 * MB);     // 4MB
  unsigned short* ao = (unsigned short*)(ws + 8 * MB);     // 4MB
  unsigned short* y1 = (unsigned short*)(ws + 28 * MB);    // 4MB
  unsigned short* h1 = (unsigned short*)(ws + 0);          // 16MB FFN phase
  float* u = (float*)(ws + 32 * MB);                       // 8MB
  unsigned short* wcat = (unsigned short*)(ws + 40 * MB);  // 2MB
  unsigned short* wot = (unsigned short*)(ws + 42 * MB);   // 0.5MB
  unsigned short* w1t = (unsigned short*)(ws + 42 * MB + 512 * 1024);
  unsigned short* w2t = (unsigned short*)(ws + 44 * MB + 512 * 1024);
  float* bcat = (float*)(ws + 46 * MB + 512 * 1024);
  unsigned short* vtb = (unsigned short*)(ws + 48 * MB);   // 4MB [2][8][64][2048]
  float* x2 = (float*)d_out;

  // batched transposes + bias concat (z=5)
  k_transw5<<<dim3(8, 8, 6), 256, 0, stream>>>(Wq, Wk, Wv, Wg, Wo, wcat, wot,
                                               bq, bk, bv, bg, bcat);
  k_transw<<<dim3(8, 32), 256, 0, stream>>>(W1, w1t, 512, 2048);
  k_transw<<<dim3(32, 8), 256, 0, stream>>>(W2, w2t, 2048, 512);

  k_ln<<<4096, 256, 0, stream>>>(x, ln1g, ln1b, y1);
  k_gemm<128><<<dim3(32, 32), 256, 0, stream>>>(y1, wcat, bcat, 4096, 2048, 512, 6,
                                                u, qb, nullptr, nullptr, vtb);
  k_attn16f<<<256, 512, 0, stream>>>(qb, kb, vtb, abias, amask, ao);
  k_gemm<64><<<dim3(64, 8), 256, 0, stream>>>(ao, wot, bo, 4096, 512, 512, 3,
                                              x2, nullptr, u, x, nullptr);
  k_ln<<<4096, 256, 0, stream>>>(x2, ln2g, ln2b, y1);
  k_gemm<128><<<dim3(32, 32), 256, 0, stream>>>(y1, w1t, b1, 4096, 2048, 512, 4,
                                                nullptr, h1, nullptr, nullptr, nullptr);
  k_gemm<64><<<dim3(64, 8), 256, 0, stream>>>(h1, w2t, b2, 4096, 512, 2048, 5,
                                              outp, nullptr, x2, nullptr, nullptr);
}